// Round 2
// baseline (277.077 us; speedup 1.0000x reference)
//
#include <hip/hip_runtime.h>
#include <hip/hip_bf16.h>

#define B_ 2
#define T_ 2048
#define H_ 16
#define DH_ 64
#define D_ 1024

typedef __hip_bfloat16 bf16;
typedef __attribute__((ext_vector_type(4))) float f32x4;
typedef __attribute__((ext_vector_type(8))) short s16x8;
typedef __attribute__((ext_vector_type(4))) short s16x4;
typedef __attribute__((ext_vector_type(4))) unsigned short u16x4;

#if defined(__HIP_DEVICE_COMPILE__)
#if !__has_builtin(__builtin_amdgcn_mfma_f32_16x16x32_bf16)
#error "missing __builtin_amdgcn_mfma_f32_16x16x32_bf16"
#endif
#if !__has_builtin(__builtin_amdgcn_mfma_f32_16x16x16bf16_1k)
#error "missing __builtin_amdgcn_mfma_f32_16x16x16bf16_1k"
#endif
#endif

__device__ __forceinline__ unsigned short f2bf_bits(float f) {
  bf16 h = __float2bfloat16(f);
  return *reinterpret_cast<unsigned short*>(&h);
}

__device__ __forceinline__ void gload_lds16(const bf16* g, bf16* l) {
  __builtin_amdgcn_global_load_lds(
      (const __attribute__((address_space(1))) void*)g,
      (__attribute__((address_space(3))) void*)l, 16, 0, 0);
}

// ---------------- prep kernels ----------------

__global__ void k_f32_to_bf16(const float* __restrict__ in, bf16* __restrict__ out, int n4) {
  int i = blockIdx.x * blockDim.x + threadIdx.x;
  if (i >= n4) return;
  float4 v = reinterpret_cast<const float4*>(in)[i];
  u16x4 o;
  o[0] = f2bf_bits(v.x); o[1] = f2bf_bits(v.y);
  o[2] = f2bf_bits(v.z); o[3] = f2bf_bits(v.w);
  reinterpret_cast<u16x4*>(out)[i] = o;
}

// in: [R][C] f32 row-major; out: [C][R] bf16 row-major
__global__ void k_transpose_f32_bf16(const float* __restrict__ in, bf16* __restrict__ out,
                                     int R, int C) {
  __shared__ float t[32][33];
  int c0 = blockIdx.x * 32, r0 = blockIdx.y * 32;
  int tx = threadIdx.x, ty = threadIdx.y;
  #pragma unroll
  for (int i = 0; i < 32; i += 8)
    t[ty + i][tx] = in[(size_t)(r0 + ty + i) * C + (c0 + tx)];
  __syncthreads();
  #pragma unroll
  for (int i = 0; i < 32; i += 8)
    out[(size_t)(c0 + ty + i) * R + (r0 + tx)] = __float2bfloat16(t[tx][ty + i]);
}

__global__ void k_rope_tab(float2* __restrict__ cs) {
  int i = blockIdx.x * blockDim.x + threadIdx.x;
  if (i >= T_ * 32) return;
  int t = i >> 5, f = i & 31;
  float inv = powf(10000.0f, -(float)f / 32.0f);
  float a = (float)t * inv;
  cs[i] = make_float2(cosf(a), sinf(a));
}

// ---------------- GEMM: C = A[M][K] * (Bt[N][K])^T + bias ----------------
// EPI=0: QKV epilogue (RoPE + scatter q/k/v bf16 [B,H,T,DH])
// EPI=1: plain f32 store to outF [M][N]
template <int EPI>
__global__ __launch_bounds__(256)
void gemm_bt(const bf16* __restrict__ A, const bf16* __restrict__ Bt,
             const float* __restrict__ bias, float* __restrict__ outF,
             bf16* __restrict__ qb, bf16* __restrict__ kb, bf16* __restrict__ vb,
             const float2* __restrict__ cs, int M, int N, int K) {
  __shared__ __align__(16) bf16 As[128 * 32];
  __shared__ __align__(16) bf16 Bs[128 * 32];
  const int tid = threadIdx.x;
  const int w = tid >> 6, l = tid & 63;
  const int wr = w >> 1, wc = w & 1;
  const int m0 = blockIdx.y * 128, n0 = blockIdx.x * 128;
  const int l15 = l & 15, l4 = l >> 4;
  const int srow = w * 16 + (l >> 2);   // staged row within 64-row round
  const int scol = (l & 3) * 8;         // staged k-element offset
  f32x4 acc[4][4] = {};

  for (int k0 = 0; k0 < K; k0 += 32) {
    #pragma unroll
    for (int r = 0; r < 2; ++r) {
      const int row = r * 64 + srow;
      gload_lds16(A + (size_t)(m0 + row) * K + k0 + scol, As + (r * 64 + w * 16) * 32 + l * 8);
      gload_lds16(Bt + (size_t)(n0 + row) * K + k0 + scol, Bs + (r * 64 + w * 16) * 32 + l * 8);
    }
    __syncthreads();
    s16x8 af[4], bfr[4];
    #pragma unroll
    for (int i = 0; i < 4; ++i) {
      af[i]  = *(const s16x8*)(As + (wr * 64 + i * 16 + l15) * 32 + l4 * 8);
      bfr[i] = *(const s16x8*)(Bs + (wc * 64 + i * 16 + l15) * 32 + l4 * 8);
    }
    #pragma unroll
    for (int i = 0; i < 4; ++i)
      #pragma unroll
      for (int j = 0; j < 4; ++j)
        acc[i][j] = __builtin_amdgcn_mfma_f32_16x16x32_bf16(af[i], bfr[j], acc[i][j], 0, 0, 0);
    __syncthreads();
  }

  if (EPI == 1) {
    #pragma unroll
    for (int i = 0; i < 4; ++i)
      #pragma unroll
      for (int j = 0; j < 4; ++j) {
        const int ng = n0 + wc * 64 + j * 16 + l15;
        const float bv = bias[ng];
        #pragma unroll
        for (int jj = 0; jj < 4; ++jj) {
          const int mg = m0 + wr * 64 + i * 16 + l4 * 4 + jj;
          outF[(size_t)mg * N + ng] = acc[i][j][jj] + bv;
        }
      }
  } else {
    #pragma unroll
    for (int i = 0; i < 4; ++i)
      #pragma unroll
      for (int jj = 0; jj < 4; ++jj) {
        const int mg = m0 + wr * 64 + i * 16 + l4 * 4 + jj;
        const int t = mg & (T_ - 1);
        const int b = mg >> 11;
        #pragma unroll
        for (int j = 0; j < 4; ++j) {
          const int ng = n0 + wc * 64 + j * 16 + l15;
          float v = acc[i][j][jj] + bias[ng];
          float p = __shfl_xor(v, 1);  // RoPE pair partner: col ^ 1 == lane ^ 1
          const int part = ng >> 10;   // 0=q 1=k 2=v
          const int d = ng & 63;
          const int h = (ng >> 6) & 15;
          float o;
          if (part < 2) {
            float2 csv = cs[t * 32 + (d >> 1)];
            o = (d & 1) ? (v * csv.x + p * csv.y) : (v * csv.x - p * csv.y);
          } else {
            o = v;
          }
          bf16* dst = (part == 0) ? qb : (part == 1) ? kb : vb;
          dst[(size_t)((b * H_ + h) * T_ + t) * DH_ + d] = __float2bfloat16(o);
        }
      }
  }
}

// ---------------- flash attention (swapped-operand, 1 wave / 16 q-rows) ----------------
// q/k/v: bf16 [B*H][T][DH]; y: bf16 [B][T][D]
__global__ __launch_bounds__(64)
void attn_fwd(const bf16* __restrict__ qb, const bf16* __restrict__ kb,
              const bf16* __restrict__ vb, bf16* __restrict__ y) {
  const int bid = blockIdx.x;
  const int qt = bid & (T_ / 16 - 1);
  const int bh = bid >> 7;
  const int l = threadIdx.x;
  const int l15 = l & 15, l4 = l >> 4;
  const bf16* qp = qb + ((size_t)bh * T_ + qt * 16) * DH_;
  const bf16* kp = kb + (size_t)bh * T_ * DH_;
  const bf16* vp = vb + (size_t)bh * T_ * DH_;

  // B-operand fragments of Q^T: lane l holds Q[row l&15][(l>>4)*8 + 0..7 (+32)]
  const s16x8 qf0 = *(const s16x8*)(qp + l15 * DH_ + l4 * 8);
  const s16x8 qf1 = *(const s16x8*)(qp + l15 * DH_ + l4 * 8 + 32);

  f32x4 O[4] = {};  // O^T: col = q = l&15, row(d_local) = l4*4 + j, tiles dt*16
  float mrun = -INFINITY, lsum = 0.0f;

  for (int kt = 0; kt <= qt; ++kt) {
    const bf16* kr = kp + kt * 16 * DH_;
    const s16x8 kf0 = *(const s16x8*)(kr + l15 * DH_ + l4 * 8);
    const s16x8 kf1 = *(const s16x8*)(kr + l15 * DH_ + l4 * 8 + 32);
    f32x4 sT = {};
    sT = __builtin_amdgcn_mfma_f32_16x16x32_bf16(kf0, qf0, sT, 0, 0, 0);
    sT = __builtin_amdgcn_mfma_f32_16x16x32_bf16(kf1, qf1, sT, 0, 0, 0);
    // S^T: row = k_local = l4*4+j, col = q = l15
    float s[4];
    #pragma unroll
    for (int j = 0; j < 4; ++j) {
      s[j] = sT[j] * 0.125f;
      if (kt == qt && (l4 * 4 + j) > l15) s[j] = -INFINITY;  // causal mask
    }
    float tmax = fmaxf(fmaxf(s[0], s[1]), fmaxf(s[2], s[3]));
    tmax = fmaxf(tmax, __shfl_xor(tmax, 16));
    tmax = fmaxf(tmax, __shfl_xor(tmax, 32));
    const float mn = fmaxf(mrun, tmax);
    const float alpha = __expf(mrun - mn);  // first iter: exp(-inf)=0
    float p[4];
    #pragma unroll
    for (int j = 0; j < 4; ++j) p[j] = __expf(s[j] - mn);
    float ts = (p[0] + p[1]) + (p[2] + p[3]);
    ts += __shfl_xor(ts, 16);
    ts += __shfl_xor(ts, 32);
    lsum = lsum * alpha + ts;
    mrun = mn;
    #pragma unroll
    for (int dt = 0; dt < 4; ++dt) {
      O[dt][0] *= alpha; O[dt][1] *= alpha; O[dt][2] *= alpha; O[dt][3] *= alpha;
    }
    // P^T in D-layout == B-layout of 16x16x16 mfma: zero movement
    s16x4 pb;
    pb[0] = (short)f2bf_bits(p[0]); pb[1] = (short)f2bf_bits(p[1]);
    pb[2] = (short)f2bf_bits(p[2]); pb[3] = (short)f2bf_bits(p[3]);
    // A-operand = V^T tile: lane l needs V[kt*16 + l4*4 + j][dt*16 + l15]
    const unsigned short* vr =
        (const unsigned short*)(vp + (size_t)(kt * 16 + l4 * 4) * DH_ + l15);
    #pragma unroll
    for (int dt = 0; dt < 4; ++dt) {
      s16x4 vf;
      #pragma unroll
      for (int j = 0; j < 4; ++j) vf[j] = (short)vr[j * DH_ + dt * 16];
      O[dt] = __builtin_amdgcn_mfma_f32_16x16x16bf16_1k(vf, pb, O[dt], 0, 0, 0);
    }
  }

  const float inv = 1.0f / lsum;
  const int b = bh >> 4, h = bh & 15;
  bf16* yr = y + ((size_t)(b * T_ + qt * 16 + l15)) * D_ + h * DH_;
  #pragma unroll
  for (int dt = 0; dt < 4; ++dt) {
    u16x4 ov;
    #pragma unroll
    for (int j = 0; j < 4; ++j) ov[j] = f2bf_bits(O[dt][j] * inv);
    *(u16x4*)(yr + dt * 16 + l4 * 4) = ov;  // 8B packed store (d contiguous over j)
  }
}

// ---------------- launcher ----------------

extern "C" void kernel_launch(void* const* d_in, const int* in_sizes, int n_in,
                              void* d_out, int out_size, void* d_ws, size_t ws_size,
                              hipStream_t stream) {
  (void)in_sizes; (void)n_in; (void)out_size; (void)ws_size;
  const float* x     = (const float*)d_in[0];
  const float* Wqkv  = (const float*)d_in[1];
  const float* bqkv  = (const float*)d_in[2];
  const float* Wproj = (const float*)d_in[3];
  const float* bproj = (const float*)d_in[4];
  float* outF = (float*)d_out;

  const size_t NTOK = (size_t)B_ * T_;        // 4096
  const size_t NELM = NTOK * D_;              // 4,194,304

  char* p = (char*)d_ws;
  bf16* xb     = (bf16*)p; p += NELM * 2;                 // x in bf16
  bf16* wqkvT  = (bf16*)p; p += (size_t)3 * D_ * D_ * 2;  // [3072][1024]
  bf16* wprojT = (bf16*)p; p += (size_t)D_ * D_ * 2;      // [1024][1024]
  bf16* qbuf   = (bf16*)p; p += NELM * 2;                 // [B*H][T][DH]
  bf16* kbuf   = (bf16*)p; p += NELM * 2;
  bf16* vbuf   = (bf16*)p; p += NELM * 2;
  bf16* ybuf   = (bf16*)p; p += NELM * 2;                 // [B][T][D]
  float2* cs   = (float2*)p; p += (size_t)T_ * 32 * sizeof(float2);

  // prep
  k_f32_to_bf16<<<dim3((unsigned)(NELM / 4 / 256)), dim3(256), 0, stream>>>(x, xb, (int)(NELM / 4));
  k_transpose_f32_bf16<<<dim3(3 * D_ / 32, D_ / 32), dim3(32, 8), 0, stream>>>(Wqkv, wqkvT, D_, 3 * D_);
  k_transpose_f32_bf16<<<dim3(D_ / 32, D_ / 32), dim3(32, 8), 0, stream>>>(Wproj, wprojT, D_, D_);
  k_rope_tab<<<dim3(T_ * 32 / 256), dim3(256), 0, stream>>>(cs);

  // QKV projection + RoPE + head-major scatter
  gemm_bt<0><<<dim3(3 * D_ / 128, NTOK / 128), dim3(256), 0, stream>>>(
      xb, wqkvT, bqkv, nullptr, qbuf, kbuf, vbuf, cs, (int)NTOK, 3 * D_, D_);

  // causal flash attention
  attn_fwd<<<dim3((unsigned)(B_ * H_ * (T_ / 16))), dim3(64), 0, stream>>>(qbuf, kbuf, vbuf, ybuf);

  // output projection (f32 out)
  gemm_bt<1><<<dim3(D_ / 128, NTOK / 128), dim3(256), 0, stream>>>(
      ybuf, wprojT, bproj, outF, nullptr, nullptr, nullptr, cs, (int)NTOK, D_, D_);
}

// Round 3
// 197.080 us; speedup vs baseline: 1.4059x; 1.4059x over previous
//
#include <hip/hip_runtime.h>
#include <hip/hip_bf16.h>

#define B_ 2
#define T_ 2048
#define H_ 16
#define DH_ 64
#define D_ 1024
#define QBLK 64
#define KVBLK 64

typedef __hip_bfloat16 bf16;
typedef __attribute__((ext_vector_type(4))) float f32x4;
typedef __attribute__((ext_vector_type(8))) short s16x8;
typedef __attribute__((ext_vector_type(4))) short s16x4;
typedef __attribute__((ext_vector_type(4))) unsigned short u16x4;

__device__ __forceinline__ unsigned short f2bf_bits(float f) {
  bf16 h = __float2bfloat16(f);
  return *reinterpret_cast<unsigned short*>(&h);
}

__device__ __forceinline__ void gload_lds16(const bf16* g, bf16* l) {
  __builtin_amdgcn_global_load_lds(
      (const __attribute__((address_space(1))) void*)g,
      (__attribute__((address_space(3))) void*)l, 16, 0, 0);
}

// ---------------- prep kernels ----------------

__global__ void k_f32_to_bf16(const float* __restrict__ in, bf16* __restrict__ out, int n4) {
  int i = blockIdx.x * blockDim.x + threadIdx.x;
  if (i >= n4) return;
  float4 v = reinterpret_cast<const float4*>(in)[i];
  u16x4 o;
  o[0] = f2bf_bits(v.x); o[1] = f2bf_bits(v.y);
  o[2] = f2bf_bits(v.z); o[3] = f2bf_bits(v.w);
  reinterpret_cast<u16x4*>(out)[i] = o;
}

__global__ void k_transpose_f32_bf16(const float* __restrict__ in, bf16* __restrict__ out,
                                     int R, int C) {
  __shared__ float t[32][33];
  int c0 = blockIdx.x * 32, r0 = blockIdx.y * 32;
  int tx = threadIdx.x, ty = threadIdx.y;
  #pragma unroll
  for (int i = 0; i < 32; i += 8)
    t[ty + i][tx] = in[(size_t)(r0 + ty + i) * C + (c0 + tx)];
  __syncthreads();
  #pragma unroll
  for (int i = 0; i < 32; i += 8)
    out[(size_t)(c0 + ty + i) * R + (r0 + tx)] = __float2bfloat16(t[tx][ty + i]);
}

__global__ void k_rope_tab(float2* __restrict__ cs) {
  int i = blockIdx.x * blockDim.x + threadIdx.x;
  if (i >= T_ * 32) return;
  int t = i >> 5, f = i & 31;
  float inv = powf(10000.0f, -(float)f / 32.0f);
  float a = (float)t * inv;
  cs[i] = make_float2(cosf(a), sinf(a));
}

// ---------------- GEMM: C = A[M][K] * (Bt[N][K])^T + bias ----------------
// EPI=0: QKV epilogue: RoPE + scatter q,k row-major [B*H][T][DH]; v TRANSPOSED [B*H][DH][T]
// EPI=1: plain f32 store to outF [M][N]
template <int EPI>
__global__ __launch_bounds__(256)
void gemm_bt(const bf16* __restrict__ A, const bf16* __restrict__ Bt,
             const float* __restrict__ bias, float* __restrict__ outF,
             bf16* __restrict__ qb, bf16* __restrict__ kb, bf16* __restrict__ vb,
             const float2* __restrict__ cs, int M, int N, int K) {
  __shared__ __align__(16) bf16 As[128 * 32];
  __shared__ __align__(16) bf16 Bs[128 * 32];
  const int tid = threadIdx.x;
  const int w = tid >> 6, l = tid & 63;
  const int wr = w >> 1, wc = w & 1;
  const int m0 = blockIdx.y * 128, n0 = blockIdx.x * 128;
  const int l15 = l & 15, l4 = l >> 4;
  const int srow = w * 16 + (l >> 2);
  const int scol = (l & 3) * 8;
  f32x4 acc[4][4] = {};

  for (int k0 = 0; k0 < K; k0 += 32) {
    #pragma unroll
    for (int r = 0; r < 2; ++r) {
      const int row = r * 64 + srow;
      gload_lds16(A + (size_t)(m0 + row) * K + k0 + scol, As + (r * 64 + w * 16) * 32 + l * 8);
      gload_lds16(Bt + (size_t)(n0 + row) * K + k0 + scol, Bs + (r * 64 + w * 16) * 32 + l * 8);
    }
    __syncthreads();
    s16x8 af[4], bfr[4];
    #pragma unroll
    for (int i = 0; i < 4; ++i) {
      af[i]  = *(const s16x8*)(As + (wr * 64 + i * 16 + l15) * 32 + l4 * 8);
      bfr[i] = *(const s16x8*)(Bs + (wc * 64 + i * 16 + l15) * 32 + l4 * 8);
    }
    #pragma unroll
    for (int i = 0; i < 4; ++i)
      #pragma unroll
      for (int j = 0; j < 4; ++j)
        acc[i][j] = __builtin_amdgcn_mfma_f32_16x16x32_bf16(af[i], bfr[j], acc[i][j], 0, 0, 0);
    __syncthreads();
  }

  if (EPI == 1) {
    #pragma unroll
    for (int i = 0; i < 4; ++i)
      #pragma unroll
      for (int j = 0; j < 4; ++j) {
        const int ng = n0 + wc * 64 + j * 16 + l15;
        const float bv = bias[ng];
        #pragma unroll
        for (int jj = 0; jj < 4; ++jj) {
          const int mg = m0 + wr * 64 + i * 16 + l4 * 4 + jj;
          outF[(size_t)mg * N + ng] = acc[i][j][jj] + bv;
        }
      }
  } else {
    #pragma unroll
    for (int i = 0; i < 4; ++i)
      #pragma unroll
      for (int j = 0; j < 4; ++j) {
        const int ng = n0 + wc * 64 + j * 16 + l15;
        const int part = ng >> 10;   // wave-uniform per (i,j)
        const int d = ng & 63;
        const int h = (ng >> 6) & 15;
        const float bv = bias[ng];
        if (part == 2) {
          // v: transposed store [B*H][DH][T]; 4 consecutive t -> one 8B store
          const int mg0 = m0 + wr * 64 + i * 16 + l4 * 4;
          const int t0 = mg0 & (T_ - 1);
          const int b = mg0 >> 11;
          u16x4 ov;
          #pragma unroll
          for (int jj = 0; jj < 4; ++jj) ov[jj] = f2bf_bits(acc[i][j][jj] + bv);
          *(u16x4*)(vb + ((size_t)(b * H_ + h) * DH_ + d) * T_ + t0) = ov;
        } else {
          #pragma unroll
          for (int jj = 0; jj < 4; ++jj) {
            const int mg = m0 + wr * 64 + i * 16 + l4 * 4 + jj;
            const int t = mg & (T_ - 1);
            const int b = mg >> 11;
            float v = acc[i][j][jj] + bv;
            float pp = __shfl_xor(v, 1);  // RoPE pair: col ^ 1 == lane ^ 1
            float2 csv = cs[t * 32 + (d >> 1)];
            float o = (d & 1) ? (v * csv.x + pp * csv.y) : (v * csv.x - pp * csv.y);
            bf16* dst = (part == 0) ? qb : kb;
            dst[(size_t)((b * H_ + h) * T_ + t) * DH_ + d] = __float2bfloat16(o);
          }
        }
      }
  }
}

// ---------------- flash attention v2 ----------------
// 4 waves/block, QBLK=64 (16 q-rows/wave), KVBLK=64, K + V^T LDS double-buffered.
// q,k: [B*H][T][64] row-major; vt: [B*H][64][T]; y: bf16 [B][T][D]
__global__ __launch_bounds__(256)
void attn_fwd(const bf16* __restrict__ qb, const bf16* __restrict__ kb,
              const bf16* __restrict__ vtb, bf16* __restrict__ y) {
  __shared__ __align__(16) bf16 Ks[2][KVBLK * 64];
  __shared__ __align__(16) bf16 Vs[2][64 * KVBLK];

  const int tid = threadIdx.x;
  const int w = tid >> 6, l = tid & 63;
  const int l15 = l & 15, l4 = l >> 4;
  const int bid = blockIdx.x;
  const int qt = 31 - (bid & 31);   // heavy tiles first
  const int bh = bid >> 5;
  const int q0 = qt * QBLK;
  const int wq = q0 + w * 16;       // wave's first q row

  const bf16* qp = qb + ((size_t)bh * T_ + wq) * DH_;
  const bf16* kp = kb + (size_t)bh * T_ * DH_;
  const bf16* vtp = vtb + (size_t)bh * DH_ * T_;

  const s16x8 qf0 = *(const s16x8*)(qp + l15 * DH_ + l4 * 8);
  const s16x8 qf1 = *(const s16x8*)(qp + l15 * DH_ + l4 * 8 + 32);

  // staging geometry: per pass, wave w covers 8 rows; XOR-swizzled SOURCE slot
  const int srow8 = l >> 3;                    // row within wave's 8-row group
  const int sslot = (l & 7) ^ (srow8 & 7);     // source 16B-slot (dest slot = l&7)

  const int nkt = q0 / KVBLK + 1;

  f32x4 O[4] = {};
  float mrun = -INFINITY, lsum = 0.0f;
  const float SCL2 = 0.125f * 1.44269504089f;  // 1/sqrt(64) * log2(e)

  // ---- stage tile kt into buffer b ----
  auto stage = [&](int kt, int b) {
    #pragma unroll
    for (int p = 0; p < 2; ++p) {
      const int r = p * 32 + w * 8 + srow8;          // tile row (k for K, d for V^T)
      bf16* kdst = &Ks[b][(p * 32 + w * 8) * 64] + l * 8;
      bf16* vdst = &Vs[b][(p * 32 + w * 8) * 64] + l * 8;
      gload_lds16(kp + (size_t)(kt * KVBLK + r) * DH_ + sslot * 8, kdst);
      gload_lds16(vtp + (size_t)r * T_ + kt * KVBLK + sslot * 8, vdst);
    }
  };

  stage(0, 0);
  __syncthreads();

  int buf = 0;
  for (int kt = 0; kt < nkt; ++kt) {
    if (kt + 1 < nkt) stage(kt + 1, buf ^ 1);

    const int k0 = kt * KVBLK;
    const bool active = (k0 <= wq + 15);
    if (active) {
      // ---- QK^T: S^T[k][q] per 16x16 subtile ----
      float s[4][4];
      const int rsw = l15 & 7;
      #pragma unroll
      for (int ks = 0; ks < 4; ++ks) {
        const bf16* krow = &Ks[buf][(ks * 16 + l15) * 64];
        s16x8 kf0 = *(const s16x8*)(krow + ((l4 ^ rsw) * 8));
        s16x8 kf1 = *(const s16x8*)(krow + (((4 + l4) ^ rsw) * 8));
        f32x4 sT = {};
        sT = __builtin_amdgcn_mfma_f32_16x16x32_bf16(kf0, qf0, sT, 0, 0, 0);
        sT = __builtin_amdgcn_mfma_f32_16x16x32_bf16(kf1, qf1, sT, 0, 0, 0);
        #pragma unroll
        for (int j = 0; j < 4; ++j) s[ks][j] = sT[j] * SCL2;
      }
      // causal mask (only when tile not fully visible to this wave)
      if (k0 + KVBLK - 1 > wq) {
        const int q = wq + l15;
        #pragma unroll
        for (int ks = 0; ks < 4; ++ks)
          #pragma unroll
          for (int j = 0; j < 4; ++j)
            if (k0 + ks * 16 + l4 * 4 + j > q) s[ks][j] = -INFINITY;
      }
      // ---- online softmax (base-2) ----
      float tmax = -INFINITY;
      #pragma unroll
      for (int ks = 0; ks < 4; ++ks)
        #pragma unroll
        for (int j = 0; j < 4; ++j) tmax = fmaxf(tmax, s[ks][j]);
      tmax = fmaxf(tmax, __shfl_xor(tmax, 16));
      tmax = fmaxf(tmax, __shfl_xor(tmax, 32));
      const float mn = fmaxf(mrun, tmax);
      const float alpha = exp2f(mrun - mn);
      float p[4][4];
      float ts = 0.0f;
      #pragma unroll
      for (int ks = 0; ks < 4; ++ks)
        #pragma unroll
        for (int j = 0; j < 4; ++j) { p[ks][j] = exp2f(s[ks][j] - mn); ts += p[ks][j]; }
      ts += __shfl_xor(ts, 16);
      ts += __shfl_xor(ts, 32);
      lsum = lsum * alpha + ts;
      mrun = mn;
      #pragma unroll
      for (int dt = 0; dt < 4; ++dt) {
        O[dt][0] *= alpha; O[dt][1] *= alpha; O[dt][2] *= alpha; O[dt][3] *= alpha;
      }
      // ---- PV: O^T += V^T * P^T (16x16x16, P^T D-layout == B-layout) ----
      #pragma unroll
      for (int ks = 0; ks < 4; ++ks) {
        s16x4 pb;
        pb[0] = (short)f2bf_bits(p[ks][0]); pb[1] = (short)f2bf_bits(p[ks][1]);
        pb[2] = (short)f2bf_bits(p[ks][2]); pb[3] = (short)f2bf_bits(p[ks][3]);
        const int kk = ks * 16 + l4 * 4;
        const int slotbase = kk >> 3;          // = ks*2 + (l4>>1)
        const int inoff = (l4 & 1) * 8;        // byte offset within 16B slot
        #pragma unroll
        for (int dt = 0; dt < 4; ++dt) {
          const int d = dt * 16 + l15;
          const char* vrow = (const char*)&Vs[buf][d * 64];
          u16x4 vf = *(const u16x4*)(vrow + ((slotbase ^ (d & 7)) * 16 + inoff));
          O[dt] = __builtin_amdgcn_mfma_f32_16x16x16bf16_1k(
              *(const s16x4*)&vf, pb, O[dt], 0, 0, 0);
        }
      }
    }
    __syncthreads();   // drains vmcnt: next buffer staged; this buffer free
    buf ^= 1;
  }

  const float inv = 1.0f / lsum;
  const int b = bh >> 4, h = bh & 15;
  bf16* yr = y + ((size_t)(b * T_ + wq + l15)) * D_ + h * DH_;
  #pragma unroll
  for (int dt = 0; dt < 4; ++dt) {
    u16x4 ov;
    #pragma unroll
    for (int j = 0; j < 4; ++j) ov[j] = f2bf_bits(O[dt][j] * inv);
    *(u16x4*)(yr + dt * 16 + l4 * 4) = ov;
  }
}

// ---------------- launcher ----------------

extern "C" void kernel_launch(void* const* d_in, const int* in_sizes, int n_in,
                              void* d_out, int out_size, void* d_ws, size_t ws_size,
                              hipStream_t stream) {
  (void)in_sizes; (void)n_in; (void)out_size; (void)ws_size;
  const float* x     = (const float*)d_in[0];
  const float* Wqkv  = (const float*)d_in[1];
  const float* bqkv  = (const float*)d_in[2];
  const float* Wproj = (const float*)d_in[3];
  const float* bproj = (const float*)d_in[4];
  float* outF = (float*)d_out;

  const size_t NTOK = (size_t)B_ * T_;
  const size_t NELM = NTOK * D_;

  char* p = (char*)d_ws;
  bf16* xb     = (bf16*)p; p += NELM * 2;
  bf16* wqkvT  = (bf16*)p; p += (size_t)3 * D_ * D_ * 2;
  bf16* wprojT = (bf16*)p; p += (size_t)D_ * D_ * 2;
  bf16* qbuf   = (bf16*)p; p += NELM * 2;                 // [B*H][T][DH]
  bf16* kbuf   = (bf16*)p; p += NELM * 2;                 // [B*H][T][DH]
  bf16* vtbuf  = (bf16*)p; p += NELM * 2;                 // [B*H][DH][T]  (transposed)
  bf16* ybuf   = (bf16*)p; p += NELM * 2;                 // [B][T][D]
  float2* cs   = (float2*)p; p += (size_t)T_ * 32 * sizeof(float2);

  k_f32_to_bf16<<<dim3((unsigned)(NELM / 4 / 256)), dim3(256), 0, stream>>>(x, xb, (int)(NELM / 4));
  k_transpose_f32_bf16<<<dim3(3 * D_ / 32, D_ / 32), dim3(32, 8), 0, stream>>>(Wqkv, wqkvT, D_, 3 * D_);
  k_transpose_f32_bf16<<<dim3(D_ / 32, D_ / 32), dim3(32, 8), 0, stream>>>(Wproj, wprojT, D_, D_);
  k_rope_tab<<<dim3(T_ * 32 / 256), dim3(256), 0, stream>>>(cs);

  gemm_bt<0><<<dim3(3 * D_ / 128, NTOK / 128), dim3(256), 0, stream>>>(
      xb, wqkvT, bqkv, nullptr, qbuf, kbuf, vtbuf, cs, (int)NTOK, 3 * D_, D_);

  attn_fwd<<<dim3((unsigned)(B_ * H_ * (T_ / QBLK))), dim3(256), 0, stream>>>(
      qbuf, kbuf, vtbuf, ybuf);

  gemm_bt<1><<<dim3(D_ / 128, NTOK / 128), dim3(256), 0, stream>>>(
      ybuf, wprojT, bproj, outF, nullptr, nullptr, nullptr, cs, (int)NTOK, D_, D_);
}

// Round 4
// 169.880 us; speedup vs baseline: 1.6310x; 1.1601x over previous
//
#include <hip/hip_runtime.h>
#include <hip/hip_bf16.h>

#define B_ 2
#define T_ 2048
#define H_ 16
#define DH_ 64
#define D_ 1024
#define KVB 128

typedef __hip_bfloat16 bf16;
typedef __attribute__((ext_vector_type(4))) float f32x4;
typedef __attribute__((ext_vector_type(8))) short s16x8;
typedef __attribute__((ext_vector_type(4))) short s16x4;
typedef __attribute__((ext_vector_type(4))) unsigned short u16x4;

__device__ __forceinline__ unsigned short f2bf_bits(float f) {
  bf16 h = __float2bfloat16(f);
  return *reinterpret_cast<unsigned short*>(&h);
}

__device__ __forceinline__ void gload_lds16(const bf16* g, bf16* l) {
  __builtin_amdgcn_global_load_lds(
      (const __attribute__((address_space(1))) void*)g,
      (__attribute__((address_space(3))) void*)l, 16, 0, 0);
}

// ---------------- prep kernels ----------------

__global__ void k_f32_to_bf16(const float* __restrict__ in, bf16* __restrict__ out, int n4) {
  int i = blockIdx.x * blockDim.x + threadIdx.x;
  if (i >= n4) return;
  float4 v = reinterpret_cast<const float4*>(in)[i];
  u16x4 o;
  o[0] = f2bf_bits(v.x); o[1] = f2bf_bits(v.y);
  o[2] = f2bf_bits(v.z); o[3] = f2bf_bits(v.w);
  reinterpret_cast<u16x4*>(out)[i] = o;
}

__global__ void k_transpose_f32_bf16(const float* __restrict__ in, bf16* __restrict__ out,
                                     int R, int C) {
  __shared__ float t[32][33];
  int c0 = blockIdx.x * 32, r0 = blockIdx.y * 32;
  int tx = threadIdx.x, ty = threadIdx.y;
  #pragma unroll
  for (int i = 0; i < 32; i += 8)
    t[ty + i][tx] = in[(size_t)(r0 + ty + i) * C + (c0 + tx)];
  __syncthreads();
  #pragma unroll
  for (int i = 0; i < 32; i += 8)
    out[(size_t)(c0 + ty + i) * R + (r0 + tx)] = __float2bfloat16(t[tx][ty + i]);
}

__global__ void k_rope_tab(float2* __restrict__ cs) {
  int i = blockIdx.x * blockDim.x + threadIdx.x;
  if (i >= T_ * 32) return;
  int t = i >> 5, f = i & 31;
  float inv = powf(10000.0f, -(float)f / 32.0f);
  float a = (float)t * inv;
  cs[i] = make_float2(cosf(a), sinf(a));
}

// ---------------- GEMM: C = A[M][K] * (Bt[N][K])^T + bias ----------------
// 1D grid with XCD swizzle. EPI=0: QKV epilogue; EPI=1: f32 store.
template <int EPI>
__global__ __launch_bounds__(256)
void gemm_bt(const bf16* __restrict__ A, const bf16* __restrict__ Bt,
             const float* __restrict__ bias, float* __restrict__ outF,
             bf16* __restrict__ qb, bf16* __restrict__ kb, bf16* __restrict__ vb,
             const float2* __restrict__ cs, int M, int N, int K) {
  __shared__ __align__(16) bf16 As[128 * 32];
  __shared__ __align__(16) bf16 Bs[128 * 32];
  const int tid = threadIdx.x;
  const int w = tid >> 6, l = tid & 63;
  const int wr = w >> 1, wc = w & 1;
  // XCD-aware swizzle (gridDim.x % 8 == 0 for both instantiations)
  const int nwg = gridDim.x;
  int bid = blockIdx.x;
  bid = (bid & 7) * (nwg >> 3) + (bid >> 3);
  const int nxb = N >> 7;
  const int m0 = (bid / nxb) * 128, n0 = (bid % nxb) * 128;
  const int l15 = l & 15, l4 = l >> 4;
  const int srow = w * 16 + (l >> 2);
  const int scol = (l & 3) * 8;
  f32x4 acc[4][4] = {};

  for (int k0 = 0; k0 < K; k0 += 32) {
    #pragma unroll
    for (int r = 0; r < 2; ++r) {
      const int row = r * 64 + srow;
      gload_lds16(A + (size_t)(m0 + row) * K + k0 + scol, As + (r * 64 + w * 16) * 32 + l * 8);
      gload_lds16(Bt + (size_t)(n0 + row) * K + k0 + scol, Bs + (r * 64 + w * 16) * 32 + l * 8);
    }
    __syncthreads();
    s16x8 af[4], bfr[4];
    #pragma unroll
    for (int i = 0; i < 4; ++i) {
      af[i]  = *(const s16x8*)(As + (wr * 64 + i * 16 + l15) * 32 + l4 * 8);
      bfr[i] = *(const s16x8*)(Bs + (wc * 64 + i * 16 + l15) * 32 + l4 * 8);
    }
    #pragma unroll
    for (int i = 0; i < 4; ++i)
      #pragma unroll
      for (int j = 0; j < 4; ++j)
        acc[i][j] = __builtin_amdgcn_mfma_f32_16x16x32_bf16(af[i], bfr[j], acc[i][j], 0, 0, 0);
    __syncthreads();
  }

  if (EPI == 1) {
    #pragma unroll
    for (int i = 0; i < 4; ++i)
      #pragma unroll
      for (int j = 0; j < 4; ++j) {
        const int ng = n0 + wc * 64 + j * 16 + l15;
        const float bv = bias[ng];
        #pragma unroll
        for (int jj = 0; jj < 4; ++jj) {
          const int mg = m0 + wr * 64 + i * 16 + l4 * 4 + jj;
          outF[(size_t)mg * N + ng] = acc[i][j][jj] + bv;
        }
      }
  } else {
    #pragma unroll
    for (int i = 0; i < 4; ++i)
      #pragma unroll
      for (int j = 0; j < 4; ++j) {
        const int ng = n0 + wc * 64 + j * 16 + l15;
        const int part = ng >> 10;
        const int d = ng & 63;
        const int h = (ng >> 6) & 15;
        const float bv = bias[ng];
        if (part == 2) {
          const int mg0 = m0 + wr * 64 + i * 16 + l4 * 4;
          const int t0 = mg0 & (T_ - 1);
          const int b = mg0 >> 11;
          u16x4 ov;
          #pragma unroll
          for (int jj = 0; jj < 4; ++jj) ov[jj] = f2bf_bits(acc[i][j][jj] + bv);
          *(u16x4*)(vb + ((size_t)(b * H_ + h) * DH_ + d) * T_ + t0) = ov;
        } else {
          #pragma unroll
          for (int jj = 0; jj < 4; ++jj) {
            const int mg = m0 + wr * 64 + i * 16 + l4 * 4 + jj;
            const int t = mg & (T_ - 1);
            const int b = mg >> 11;
            float v = acc[i][j][jj] + bv;
            float pp = __shfl_xor(v, 1);
            float2 csv = cs[t * 32 + (d >> 1)];
            float o = (d & 1) ? (v * csv.x + pp * csv.y) : (v * csv.x - pp * csv.y);
            bf16* dst = (part == 0) ? qb : kb;
            dst[(size_t)((b * H_ + h) * T_ + t) * DH_ + d] = __float2bfloat16(o);
          }
        }
      }
  }
}

// ---------------- flash attention v3 ----------------
// Pair-balanced causal: block = (bh, pi); q-tiles A=pi, B=31-pi (64 rows each),
// single kv sweep (A range subset of B range). 4 waves x 16 q-rows per tile.
// KVB=128, K[128][64] + V^T[64][128] double-buffered, XOR-swizzled.
__global__ __launch_bounds__(256, 2)
void attn_fwd(const bf16* __restrict__ qb, const bf16* __restrict__ kb,
              const bf16* __restrict__ vtb, bf16* __restrict__ y) {
  __shared__ __align__(16) bf16 Ks[2][KVB * 64];
  __shared__ __align__(16) bf16 Vs[2][64 * KVB];

  const int tid = threadIdx.x;
  const int w = tid >> 6, l = tid & 63;
  const int l15 = l & 15, l4 = l >> 4;
  const int pi = blockIdx.x & 15;
  const int bh = blockIdx.x >> 4;
  const int nkt = (33 - pi) >> 1;          // uniform-ish: 16..9, work uniform = 17
  const int wqA = pi * 64 + w * 16;
  const int wqB = (31 - pi) * 64 + w * 16;

  const bf16* qp = qb + (size_t)bh * T_ * DH_;
  const bf16* kp = kb + (size_t)bh * T_ * DH_;
  const bf16* vtp = vtb + (size_t)bh * DH_ * T_;

  const s16x8 qA0 = *(const s16x8*)(qp + (size_t)(wqA + l15) * DH_ + l4 * 8);
  const s16x8 qA1 = *(const s16x8*)(qp + (size_t)(wqA + l15) * DH_ + l4 * 8 + 32);
  const s16x8 qB0 = *(const s16x8*)(qp + (size_t)(wqB + l15) * DH_ + l4 * 8);
  const s16x8 qB1 = *(const s16x8*)(qp + (size_t)(wqB + l15) * DH_ + l4 * 8 + 32);

  // staging maps (linear LDS dest, pre-swizzled global source)
  const int krow_ = tid >> 3, kslot_ = tid & 7;    // K: row r, 8 slots of 16B
  const int vrow_ = tid >> 4, vslot_ = tid & 15;   // V: row d, 16 slots of 16B

  auto stage = [&](int kt, int b) {
    const bf16* ksrc = kp + (size_t)kt * KVB * DH_;
    #pragma unroll
    for (int p = 0; p < 4; ++p) {
      const int r = p * 32 + krow_;
      gload_lds16(ksrc + (size_t)r * DH_ + ((kslot_ ^ (r & 7)) * 8),
                  &Ks[b][r * 64 + kslot_ * 8]);
    }
    #pragma unroll
    for (int p = 0; p < 4; ++p) {
      const int r = p * 16 + vrow_;
      gload_lds16(vtp + (size_t)r * T_ + kt * KVB + ((vslot_ ^ (r & 15)) * 8),
                  &Vs[b][r * KVB + vslot_ * 8]);
    }
  };

  f32x4 OA[4] = {}, OB[4] = {};
  float mA = -INFINITY, lsA = 0.0f, mB = -INFINITY, lsB = 0.0f;
  const float SCL2 = 0.125f * 1.44269504089f;   // 1/sqrt(64) * log2(e)

  stage(0, 0);
  __syncthreads();

  int buf = 0;
  for (int kt = 0; kt < nkt; ++kt) {
    if (kt + 1 < nkt) stage(kt + 1, buf ^ 1);
    const int k0 = kt * KVB;
    const bool actA = (k0 <= wqA + 15);

    // ---- QK^T (K-frags shared by A and B) ----
    f32x4 sA[8], sB[8];
    const int rsw = l15 & 7;
    __builtin_amdgcn_s_setprio(1);
    #pragma unroll
    for (int ks = 0; ks < 8; ++ks) {
      const bf16* krow = &Ks[buf][(ks * 16 + l15) * 64];
      const s16x8 kf0 = *(const s16x8*)(krow + ((l4 ^ rsw) * 8));
      const s16x8 kf1 = *(const s16x8*)(krow + (((4 + l4) ^ rsw) * 8));
      f32x4 t = {};
      t = __builtin_amdgcn_mfma_f32_16x16x32_bf16(kf0, qB0, t, 0, 0, 0);
      t = __builtin_amdgcn_mfma_f32_16x16x32_bf16(kf1, qB1, t, 0, 0, 0);
      sB[ks] = t;
      if (actA) {
        f32x4 u = {};
        u = __builtin_amdgcn_mfma_f32_16x16x32_bf16(kf0, qA0, u, 0, 0, 0);
        u = __builtin_amdgcn_mfma_f32_16x16x32_bf16(kf1, qA1, u, 0, 0, 0);
        sA[ks] = u;
      }
    }
    __builtin_amdgcn_s_setprio(0);

    // ---- online softmax (base-2, defer-max THR=8); s -> p in place ----
    auto softmax = [&](f32x4 (&s)[8], f32x4 (&O)[4], float& m, float& lsum, int wq) {
      if (k0 + KVB - 1 > wq) {           // diagonal tile for this wave
        const int q = wq + l15;
        #pragma unroll
        for (int ks = 0; ks < 8; ++ks)
          #pragma unroll
          for (int j = 0; j < 4; ++j)
            if (k0 + ks * 16 + l4 * 4 + j > q) s[ks][j] = -1e30f;
      }
      float tmax = -1e30f;
      #pragma unroll
      for (int ks = 0; ks < 8; ++ks) {
        tmax = fmaxf(tmax, fmaxf(fmaxf(s[ks][0], s[ks][1]), fmaxf(s[ks][2], s[ks][3])));
      }
      tmax = fmaxf(tmax, __shfl_xor(tmax, 16));
      tmax = fmaxf(tmax, __shfl_xor(tmax, 32));
      const float zm = tmax * SCL2;
      if (__any(zm > m + 8.0f)) {        // rescale path
        const float mn = fmaxf(m, zm);
        const float al = exp2f(m - mn);
        lsum *= al;
        #pragma unroll
        for (int dt = 0; dt < 4; ++dt) O[dt] *= al;
        m = mn;
      }
      float ts = 0.0f;
      #pragma unroll
      for (int ks = 0; ks < 8; ++ks) {
        f32x4 pv;
        #pragma unroll
        for (int j = 0; j < 4; ++j) pv[j] = exp2f(s[ks][j] * SCL2 - m);
        s[ks] = pv;
        ts += (pv[0] + pv[1]) + (pv[2] + pv[3]);
      }
      ts += __shfl_xor(ts, 16);
      ts += __shfl_xor(ts, 32);
      lsum += ts;
    };
    softmax(sB, OB, mB, lsB, wqB);
    if (actA) softmax(sA, OA, mA, lsA, wqA);

    // ---- PV (V-frags shared by A and B) ----
    __builtin_amdgcn_s_setprio(1);
    #pragma unroll
    for (int ks = 0; ks < 8; ++ks) {
      s16x4 pbB, pbA;
      pbB[0] = (short)f2bf_bits(sB[ks][0]); pbB[1] = (short)f2bf_bits(sB[ks][1]);
      pbB[2] = (short)f2bf_bits(sB[ks][2]); pbB[3] = (short)f2bf_bits(sB[ks][3]);
      if (actA) {
        pbA[0] = (short)f2bf_bits(sA[ks][0]); pbA[1] = (short)f2bf_bits(sA[ks][1]);
        pbA[2] = (short)f2bf_bits(sA[ks][2]); pbA[3] = (short)f2bf_bits(sA[ks][3]);
      }
      const int slotb = ks * 2 + (l4 >> 1);
      const int inoff = (l4 & 1) * 8;
      #pragma unroll
      for (int dt = 0; dt < 4; ++dt) {
        const int d = dt * 16 + l15;
        const char* vrow = (const char*)&Vs[buf][d * KVB];
        u16x4 vf = *(const u16x4*)(vrow + ((slotb ^ (d & 15)) * 16 + inoff));
        OB[dt] = __builtin_amdgcn_mfma_f32_16x16x16bf16_1k(*(const s16x4*)&vf, pbB, OB[dt], 0, 0, 0);
        if (actA)
          OA[dt] = __builtin_amdgcn_mfma_f32_16x16x16bf16_1k(*(const s16x4*)&vf, pbA, OA[dt], 0, 0, 0);
      }
    }
    __builtin_amdgcn_s_setprio(0);

    __syncthreads();
    buf ^= 1;
  }

  const int b = bh >> 4, h = bh & 15;
  auto writeO = [&](f32x4 (&O)[4], float lsum, int wq) {
    const float inv = 1.0f / lsum;
    bf16* yr = y + ((size_t)(b * T_ + wq + l15)) * D_ + h * DH_;
    #pragma unroll
    for (int dt = 0; dt < 4; ++dt) {
      u16x4 ov;
      #pragma unroll
      for (int j = 0; j < 4; ++j) ov[j] = f2bf_bits(O[dt][j] * inv);
      *(u16x4*)(yr + dt * 16 + l4 * 4) = ov;
    }
  };
  writeO(OA, lsA, wqA);
  writeO(OB, lsB, wqB);
}

// ---------------- launcher ----------------

extern "C" void kernel_launch(void* const* d_in, const int* in_sizes, int n_in,
                              void* d_out, int out_size, void* d_ws, size_t ws_size,
                              hipStream_t stream) {
  (void)in_sizes; (void)n_in; (void)out_size; (void)ws_size;
  const float* x     = (const float*)d_in[0];
  const float* Wqkv  = (const float*)d_in[1];
  const float* bqkv  = (const float*)d_in[2];
  const float* Wproj = (const float*)d_in[3];
  const float* bproj = (const float*)d_in[4];
  float* outF = (float*)d_out;

  const size_t NTOK = (size_t)B_ * T_;
  const size_t NELM = NTOK * D_;

  char* p = (char*)d_ws;
  bf16* xb     = (bf16*)p; p += NELM * 2;
  bf16* wqkvT  = (bf16*)p; p += (size_t)3 * D_ * D_ * 2;
  bf16* wprojT = (bf16*)p; p += (size_t)D_ * D_ * 2;
  bf16* qbuf   = (bf16*)p; p += NELM * 2;                 // [B*H][T][DH]
  bf16* kbuf   = (bf16*)p; p += NELM * 2;                 // [B*H][T][DH]
  bf16* vtbuf  = (bf16*)p; p += NELM * 2;                 // [B*H][DH][T]
  bf16* ybuf   = (bf16*)p; p += NELM * 2;                 // [B][T][D]
  float2* cs   = (float2*)p; p += (size_t)T_ * 32 * sizeof(float2);

  k_f32_to_bf16<<<dim3((unsigned)(NELM / 4 / 256)), dim3(256), 0, stream>>>(x, xb, (int)(NELM / 4));
  k_transpose_f32_bf16<<<dim3(3 * D_ / 32, D_ / 32), dim3(32, 8), 0, stream>>>(Wqkv, wqkvT, D_, 3 * D_);
  k_transpose_f32_bf16<<<dim3(D_ / 32, D_ / 32), dim3(32, 8), 0, stream>>>(Wproj, wprojT, D_, D_);
  k_rope_tab<<<dim3(T_ * 32 / 256), dim3(256), 0, stream>>>(cs);

  gemm_bt<0><<<dim3(24 * 32), dim3(256), 0, stream>>>(
      xb, wqkvT, bqkv, nullptr, qbuf, kbuf, vtbuf, cs, (int)NTOK, 3 * D_, D_);

  attn_fwd<<<dim3(512), dim3(256), 0, stream>>>(qbuf, kbuf, vtbuf, ybuf);

  gemm_bt<1><<<dim3(8 * 32), dim3(256), 0, stream>>>(
      ybuf, wprojT, bproj, outF, nullptr, nullptr, nullptr, cs, (int)NTOK, D_, D_);
}

// Round 5
// 162.602 us; speedup vs baseline: 1.7040x; 1.0448x over previous
//
#include <hip/hip_runtime.h>
#include <hip/hip_bf16.h>

#define B_ 2
#define T_ 2048
#define H_ 16
#define DH_ 64
#define D_ 1024
#define KVB 128

typedef __hip_bfloat16 bf16;
typedef __attribute__((ext_vector_type(4))) float f32x4;
typedef __attribute__((ext_vector_type(8))) short s16x8;
typedef __attribute__((ext_vector_type(4))) short s16x4;
typedef __attribute__((ext_vector_type(4))) unsigned short u16x4;

__device__ __forceinline__ unsigned short f2bf_bits(float f) {
  bf16 h = __float2bfloat16(f);
  return *reinterpret_cast<unsigned short*>(&h);
}

__device__ __forceinline__ void gload_lds16(const bf16* g, bf16* l) {
  __builtin_amdgcn_global_load_lds(
      (const __attribute__((address_space(1))) void*)g,
      (__attribute__((address_space(3))) void*)l, 16, 0, 0);
}

// ---------------- fused prep kernel ----------------
// sections by blockIdx: [x->bf16 | Wqkv^T | Wproj^T | rope table]
#define NB_CONV 4096   // (B*T*D)/4/256
#define NB_TQ   3072   // (3072/32)*(1024/32)
#define NB_TP   1024   // (1024/32)*(1024/32)
#define NB_ROPE 256    // T*32/256

__global__ __launch_bounds__(256)
void k_prep(const float* __restrict__ x, bf16* __restrict__ xb,
            const float* __restrict__ Wqkv, bf16* __restrict__ wqkvT,
            const float* __restrict__ Wproj, bf16* __restrict__ wprojT,
            float2* __restrict__ cs) {
  __shared__ float t[32][33];
  const int tid = threadIdx.x;
  int bid = blockIdx.x;
  if (bid < NB_CONV) {
    const int i = bid * 256 + tid;
    float4 v = reinterpret_cast<const float4*>(x)[i];
    u16x4 o;
    o[0] = f2bf_bits(v.x); o[1] = f2bf_bits(v.y);
    o[2] = f2bf_bits(v.z); o[3] = f2bf_bits(v.w);
    reinterpret_cast<u16x4*>(xb)[i] = o;
    return;
  }
  bid -= NB_CONV;
  if (bid < NB_TQ + NB_TP) {
    const float* in;
    bf16* out;
    int R, C, bx, by;
    if (bid < NB_TQ) { in = Wqkv; out = wqkvT; R = 1024; C = 3072; bx = bid % 96; by = bid / 96; }
    else { int tt = bid - NB_TQ; in = Wproj; out = wprojT; R = 1024; C = 1024; bx = tt & 31; by = tt >> 5; }
    const int c0 = bx * 32, r0 = by * 32;
    const int tx = tid & 31, ty = tid >> 5;
    #pragma unroll
    for (int i = 0; i < 32; i += 8)
      t[ty + i][tx] = in[(size_t)(r0 + ty + i) * C + (c0 + tx)];
    __syncthreads();
    #pragma unroll
    for (int i = 0; i < 32; i += 8)
      out[(size_t)(c0 + ty + i) * R + (r0 + tx)] = __float2bfloat16(t[tx][ty + i]);
    return;
  }
  bid -= NB_TQ + NB_TP;
  {
    const int i = bid * 256 + tid;
    const int tt = i >> 5, f = i & 31;
    float inv = powf(10000.0f, -(float)f / 32.0f);
    float a = (float)tt * inv;
    cs[i] = make_float2(cosf(a), sinf(a));
  }
}

// ---------------- GEMM: C = A[M][K] * (Bt[N][K])^T + bias, BK=64 ----------------
// 1D grid with XCD swizzle. EPI=0: QKV epilogue; EPI=1: f32 store.
template <int EPI>
__global__ __launch_bounds__(256)
void gemm_bt(const bf16* __restrict__ A, const bf16* __restrict__ Bt,
             const float* __restrict__ bias, float* __restrict__ outF,
             bf16* __restrict__ qb, bf16* __restrict__ kb, bf16* __restrict__ vb,
             const float2* __restrict__ cs, int M, int N, int K) {
  __shared__ __align__(16) bf16 As[128 * 64];
  __shared__ __align__(16) bf16 Bs[128 * 64];
  const int tid = threadIdx.x;
  const int w = tid >> 6, l = tid & 63;
  const int wr = w >> 1, wc = w & 1;
  const int nwg = gridDim.x;
  int bid = blockIdx.x;
  bid = (bid & 7) * (nwg >> 3) + (bid >> 3);
  const int nxb = N >> 7;
  const int m0 = (bid / nxb) * 128, n0 = (bid % nxb) * 128;
  const int l15 = l & 15, l4 = l >> 4;
  const int srow = w * 8 + (l >> 3);    // staged row within 32-row round
  const int scol = (l & 7) * 8;         // staged k-element offset
  f32x4 acc[4][4] = {};

  for (int k0 = 0; k0 < K; k0 += 64) {
    #pragma unroll
    for (int p = 0; p < 4; ++p) {
      const int row = p * 32 + srow;
      bf16* adst = As + (p * 32 + w * 8) * 64 + l * 8;
      bf16* bdst = Bs + (p * 32 + w * 8) * 64 + l * 8;
      gload_lds16(A + (size_t)(m0 + row) * K + k0 + scol, adst);
      gload_lds16(Bt + (size_t)(n0 + row) * K + k0 + scol, bdst);
    }
    __syncthreads();
    s16x8 af[4][2], bfr[4][2];
    #pragma unroll
    for (int i = 0; i < 4; ++i)
      #pragma unroll
      for (int h = 0; h < 2; ++h) {
        af[i][h]  = *(const s16x8*)(As + (wr * 64 + i * 16 + l15) * 64 + h * 32 + l4 * 8);
        bfr[i][h] = *(const s16x8*)(Bs + (wc * 64 + i * 16 + l15) * 64 + h * 32 + l4 * 8);
      }
    #pragma unroll
    for (int i = 0; i < 4; ++i)
      #pragma unroll
      for (int j = 0; j < 4; ++j) {
        acc[i][j] = __builtin_amdgcn_mfma_f32_16x16x32_bf16(af[i][0], bfr[j][0], acc[i][j], 0, 0, 0);
        acc[i][j] = __builtin_amdgcn_mfma_f32_16x16x32_bf16(af[i][1], bfr[j][1], acc[i][j], 0, 0, 0);
      }
    __syncthreads();
  }

  if (EPI == 1) {
    #pragma unroll
    for (int i = 0; i < 4; ++i)
      #pragma unroll
      for (int j = 0; j < 4; ++j) {
        const int ng = n0 + wc * 64 + j * 16 + l15;
        const float bv = bias[ng];
        #pragma unroll
        for (int jj = 0; jj < 4; ++jj) {
          const int mg = m0 + wr * 64 + i * 16 + l4 * 4 + jj;
          outF[(size_t)mg * N + ng] = acc[i][j][jj] + bv;
        }
      }
  } else {
    #pragma unroll
    for (int i = 0; i < 4; ++i)
      #pragma unroll
      for (int j = 0; j < 4; ++j) {
        const int ng = n0 + wc * 64 + j * 16 + l15;
        const int part = ng >> 10;
        const int d = ng & 63;
        const int h = (ng >> 6) & 15;
        const float bv = bias[ng];
        if (part == 2) {
          const int mg0 = m0 + wr * 64 + i * 16 + l4 * 4;
          const int t0 = mg0 & (T_ - 1);
          const int b = mg0 >> 11;
          u16x4 ov;
          #pragma unroll
          for (int jj = 0; jj < 4; ++jj) ov[jj] = f2bf_bits(acc[i][j][jj] + bv);
          *(u16x4*)(vb + ((size_t)(b * H_ + h) * DH_ + d) * T_ + t0) = ov;
        } else {
          #pragma unroll
          for (int jj = 0; jj < 4; ++jj) {
            const int mg = m0 + wr * 64 + i * 16 + l4 * 4 + jj;
            const int t = mg & (T_ - 1);
            const int b = mg >> 11;
            float v = acc[i][j][jj] + bv;
            float pp = __shfl_xor(v, 1);
            float2 csv = cs[t * 32 + (d >> 1)];
            float o = (d & 1) ? (v * csv.x + pp * csv.y) : (v * csv.x - pp * csv.y);
            bf16* dst = (part == 0) ? qb : kb;
            dst[(size_t)((b * H_ + h) * T_ + t) * DH_ + d] = __float2bfloat16(o);
          }
        }
      }
  }
}

// ---------------- flash attention (pair-balanced causal, unchanged) ----------------
__global__ __launch_bounds__(256, 2)
void attn_fwd(const bf16* __restrict__ qb, const bf16* __restrict__ kb,
              const bf16* __restrict__ vtb, bf16* __restrict__ y) {
  __shared__ __align__(16) bf16 Ks[2][KVB * 64];
  __shared__ __align__(16) bf16 Vs[2][64 * KVB];

  const int tid = threadIdx.x;
  const int w = tid >> 6, l = tid & 63;
  const int l15 = l & 15, l4 = l >> 4;
  const int pi = blockIdx.x & 15;
  const int bh = blockIdx.x >> 4;
  const int nkt = (33 - pi) >> 1;
  const int wqA = pi * 64 + w * 16;
  const int wqB = (31 - pi) * 64 + w * 16;

  const bf16* qp = qb + (size_t)bh * T_ * DH_;
  const bf16* kp = kb + (size_t)bh * T_ * DH_;
  const bf16* vtp = vtb + (size_t)bh * DH_ * T_;

  const s16x8 qA0 = *(const s16x8*)(qp + (size_t)(wqA + l15) * DH_ + l4 * 8);
  const s16x8 qA1 = *(const s16x8*)(qp + (size_t)(wqA + l15) * DH_ + l4 * 8 + 32);
  const s16x8 qB0 = *(const s16x8*)(qp + (size_t)(wqB + l15) * DH_ + l4 * 8);
  const s16x8 qB1 = *(const s16x8*)(qp + (size_t)(wqB + l15) * DH_ + l4 * 8 + 32);

  const int krow_ = tid >> 3, kslot_ = tid & 7;
  const int vrow_ = tid >> 4, vslot_ = tid & 15;

  auto stage = [&](int kt, int b) {
    const bf16* ksrc = kp + (size_t)kt * KVB * DH_;
    #pragma unroll
    for (int p = 0; p < 4; ++p) {
      const int r = p * 32 + krow_;
      gload_lds16(ksrc + (size_t)r * DH_ + ((kslot_ ^ (r & 7)) * 8),
                  &Ks[b][r * 64 + kslot_ * 8]);
    }
    #pragma unroll
    for (int p = 0; p < 4; ++p) {
      const int r = p * 16 + vrow_;
      gload_lds16(vtp + (size_t)r * T_ + kt * KVB + ((vslot_ ^ (r & 15)) * 8),
                  &Vs[b][r * KVB + vslot_ * 8]);
    }
  };

  f32x4 OA[4] = {}, OB[4] = {};
  float mA = -INFINITY, lsA = 0.0f, mB = -INFINITY, lsB = 0.0f;
  const float SCL2 = 0.125f * 1.44269504089f;

  stage(0, 0);
  __syncthreads();

  int buf = 0;
  for (int kt = 0; kt < nkt; ++kt) {
    if (kt + 1 < nkt) stage(kt + 1, buf ^ 1);
    const int k0 = kt * KVB;
    const bool actA = (k0 <= wqA + 15);

    f32x4 sA[8], sB[8];
    const int rsw = l15 & 7;
    __builtin_amdgcn_s_setprio(1);
    #pragma unroll
    for (int ks = 0; ks < 8; ++ks) {
      const bf16* krow = &Ks[buf][(ks * 16 + l15) * 64];
      const s16x8 kf0 = *(const s16x8*)(krow + ((l4 ^ rsw) * 8));
      const s16x8 kf1 = *(const s16x8*)(krow + (((4 + l4) ^ rsw) * 8));
      f32x4 t = {};
      t = __builtin_amdgcn_mfma_f32_16x16x32_bf16(kf0, qB0, t, 0, 0, 0);
      t = __builtin_amdgcn_mfma_f32_16x16x32_bf16(kf1, qB1, t, 0, 0, 0);
      sB[ks] = t;
      if (actA) {
        f32x4 u = {};
        u = __builtin_amdgcn_mfma_f32_16x16x32_bf16(kf0, qA0, u, 0, 0, 0);
        u = __builtin_amdgcn_mfma_f32_16x16x32_bf16(kf1, qA1, u, 0, 0, 0);
        sA[ks] = u;
      }
    }
    __builtin_amdgcn_s_setprio(0);

    auto softmax = [&](f32x4 (&s)[8], f32x4 (&O)[4], float& m, float& lsum, int wq) {
      if (k0 + KVB - 1 > wq) {
        const int q = wq + l15;
        #pragma unroll
        for (int ks = 0; ks < 8; ++ks)
          #pragma unroll
          for (int j = 0; j < 4; ++j)
            if (k0 + ks * 16 + l4 * 4 + j > q) s[ks][j] = -1e30f;
      }
      float tmax = -1e30f;
      #pragma unroll
      for (int ks = 0; ks < 8; ++ks) {
        tmax = fmaxf(tmax, fmaxf(fmaxf(s[ks][0], s[ks][1]), fmaxf(s[ks][2], s[ks][3])));
      }
      tmax = fmaxf(tmax, __shfl_xor(tmax, 16));
      tmax = fmaxf(tmax, __shfl_xor(tmax, 32));
      const float zm = tmax * SCL2;
      if (__any(zm > m + 8.0f)) {
        const float mn = fmaxf(m, zm);
        const float al = exp2f(m - mn);
        lsum *= al;
        #pragma unroll
        for (int dt = 0; dt < 4; ++dt) O[dt] *= al;
        m = mn;
      }
      float ts = 0.0f;
      #pragma unroll
      for (int ks = 0; ks < 8; ++ks) {
        f32x4 pv;
        #pragma unroll
        for (int j = 0; j < 4; ++j) pv[j] = exp2f(s[ks][j] * SCL2 - m);
        s[ks] = pv;
        ts += (pv[0] + pv[1]) + (pv[2] + pv[3]);
      }
      ts += __shfl_xor(ts, 16);
      ts += __shfl_xor(ts, 32);
      lsum += ts;
    };
    softmax(sB, OB, mB, lsB, wqB);
    if (actA) softmax(sA, OA, mA, lsA, wqA);

    __builtin_amdgcn_s_setprio(1);
    #pragma unroll
    for (int ks = 0; ks < 8; ++ks) {
      s16x4 pbB, pbA;
      pbB[0] = (short)f2bf_bits(sB[ks][0]); pbB[1] = (short)f2bf_bits(sB[ks][1]);
      pbB[2] = (short)f2bf_bits(sB[ks][2]); pbB[3] = (short)f2bf_bits(sB[ks][3]);
      if (actA) {
        pbA[0] = (short)f2bf_bits(sA[ks][0]); pbA[1] = (short)f2bf_bits(sA[ks][1]);
        pbA[2] = (short)f2bf_bits(sA[ks][2]); pbA[3] = (short)f2bf_bits(sA[ks][3]);
      }
      const int slotb = ks * 2 + (l4 >> 1);
      const int inoff = (l4 & 1) * 8;
      #pragma unroll
      for (int dt = 0; dt < 4; ++dt) {
        const int d = dt * 16 + l15;
        const char* vrow = (const char*)&Vs[buf][d * KVB];
        u16x4 vf = *(const u16x4*)(vrow + ((slotb ^ (d & 15)) * 16 + inoff));
        OB[dt] = __builtin_amdgcn_mfma_f32_16x16x16bf16_1k(*(const s16x4*)&vf, pbB, OB[dt], 0, 0, 0);
        if (actA)
          OA[dt] = __builtin_amdgcn_mfma_f32_16x16x16bf16_1k(*(const s16x4*)&vf, pbA, OA[dt], 0, 0, 0);
      }
    }
    __builtin_amdgcn_s_setprio(0);

    __syncthreads();
    buf ^= 1;
  }

  const int b = bh >> 4, h = bh & 15;
  auto writeO = [&](f32x4 (&O)[4], float lsum, int wq) {
    const float inv = 1.0f / lsum;
    bf16* yr = y + ((size_t)(b * T_ + wq + l15)) * D_ + h * DH_;
    #pragma unroll
    for (int dt = 0; dt < 4; ++dt) {
      u16x4 ov;
      #pragma unroll
      for (int j = 0; j < 4; ++j) ov[j] = f2bf_bits(O[dt][j] * inv);
      *(u16x4*)(yr + dt * 16 + l4 * 4) = ov;
    }
  };
  writeO(OA, lsA, wqA);
  writeO(OB, lsB, wqB);
}

// ---------------- launcher ----------------

extern "C" void kernel_launch(void* const* d_in, const int* in_sizes, int n_in,
                              void* d_out, int out_size, void* d_ws, size_t ws_size,
                              hipStream_t stream) {
  (void)in_sizes; (void)n_in; (void)out_size; (void)ws_size;
  const float* x     = (const float*)d_in[0];
  const float* Wqkv  = (const float*)d_in[1];
  const float* bqkv  = (const float*)d_in[2];
  const float* Wproj = (const float*)d_in[3];
  const float* bproj = (const float*)d_in[4];
  float* outF = (float*)d_out;

  const size_t NTOK = (size_t)B_ * T_;
  const size_t NELM = NTOK * D_;

  char* p = (char*)d_ws;
  bf16* xb     = (bf16*)p; p += NELM * 2;
  bf16* wqkvT  = (bf16*)p; p += (size_t)3 * D_ * D_ * 2;
  bf16* wprojT = (bf16*)p; p += (size_t)D_ * D_ * 2;
  bf16* qbuf   = (bf16*)p; p += NELM * 2;                 // [B*H][T][DH]
  bf16* kbuf   = (bf16*)p; p += NELM * 2;                 // [B*H][T][DH]
  bf16* vtbuf  = (bf16*)p; p += NELM * 2;                 // [B*H][DH][T]
  bf16* ybuf   = (bf16*)p; p += NELM * 2;                 // [B][T][D]
  float2* cs   = (float2*)p; p += (size_t)T_ * 32 * sizeof(float2);

  k_prep<<<dim3(NB_CONV + NB_TQ + NB_TP + NB_ROPE), dim3(256), 0, stream>>>(
      x, xb, Wqkv, wqkvT, Wproj, wprojT, cs);

  gemm_bt<0><<<dim3(24 * 32), dim3(256), 0, stream>>>(
      xb, wqkvT, bqkv, nullptr, qbuf, kbuf, vtbuf, cs, (int)NTOK, 3 * D_, D_);

  attn_fwd<<<dim3(512), dim3(256), 0, stream>>>(qbuf, kbuf, vtbuf, ybuf);

  gemm_bt<1><<<dim3(8 * 32), dim3(256), 0, stream>>>(
      ybuf, wprojT, bproj, outF, nullptr, nullptr, nullptr, cs, (int)NTOK, D_, D_);
}